// Round 2
// 464.717 us; speedup vs baseline: 1.0165x; 1.0165x over previous
//
#include <hip/hip_runtime.h>
#include <hip/hip_bf16.h>
#include <stdint.h>

#define BG 64     // graphs
#define NP 256    // nodes per graph
#define DI 256    // in features
#define DO 128    // out features = clusters
#define EP 8192   // edges per graph

// ALL float tensors are FP32 (R8 probe-decoded; R9-R14 passed). Edges int32 (+int64 vote).

typedef __attribute__((ext_vector_type(8))) short short8;   // 8 bf16 (4 VGPRs)
typedef __attribute__((ext_vector_type(4))) short short4v;  // 4 bf16 (8 B)
typedef __attribute__((ext_vector_type(4))) float float4v;  // MFMA accumulator

__device__ __forceinline__ int ldi(const void* p, size_t i, int i64) {
  return i64 ? (int)((const long long*)p)[i] : ((const int*)p)[i];
}

// fp32 -> bf16 bits, round-to-nearest-even
__device__ __forceinline__ short f2b(float x) {
  union { float f; unsigned u; } c; c.f = x;
  unsigned r = c.u + 0x7FFFu + ((c.u >> 16) & 1u);
  return (short)(r >> 16);
}
__device__ __forceinline__ float b2f(short b) {
  union { unsigned u; float f; } c; c.u = ((unsigned)(unsigned short)b) << 16;
  return c.f;
}

// uniform int64-vs-int32 vote: upper words of first 8 int64 values are all 0 for int64
// data; for int32 data they are random edge values in [0,256) -> P(all zero) = 2^-64.
__device__ __forceinline__ int vote_i64(const void* esrc) {
  const uint32_t* ew = (const uint32_t*)esrc;
  int i64 = 1;
#pragma unroll
  for (int j = 0; j < 8; ++j)
    if (ew[2 * j + 1] != 0) i64 = 0;
  return i64;
}

// ---- scatter v2: LDS-accumulated row slab, NO global atomics ----
// grid (4, BG): block owns 64 dst rows of graph b. Scans all edges, LDS atomicAdd,
// streams slab out (fp32 A + exact-bf16 Abf), deg = exact integer rowsum via shfl.
__global__ __launch_bounds__(256) void k_scatter(const void* __restrict__ esrc,
                                                 const void* __restrict__ edst,
                                                 float* __restrict__ A,
                                                 short* __restrict__ Abf,
                                                 float* __restrict__ deg) {
  __shared__ float Asl[64][256];   // exactly 64 KiB
  int b = blockIdx.y, rq = blockIdx.x, t = threadIdx.x;
  float4* Az = (float4*)&Asl[0][0];
  for (int i = t; i < 64 * 256 / 4; i += 256) Az[i] = make_float4(0.f, 0.f, 0.f, 0.f);
  int i64 = vote_i64(esrc);        // uniform across block, no shared mem needed
  __syncthreads();
  const size_t base = (size_t)b * EP;
  for (int e = t; e < EP; e += 256) {
    int si = ldi(esrc, base + e, i64) & (NP - 1);
    int di = ldi(edst, base + e, i64) & (NP - 1);
    if ((di >> 6) == rq) atomicAdd(&Asl[di & 63][si], 1.0f);
  }
  __syncthreads();
  int wv = t >> 6, ln = t & 63;
#pragma unroll
  for (int k = 0; k < 16; ++k) {
    int r = k * 4 + wv;
    float4 v = *(float4*)&Asl[r][ln * 4];
    int gr = rq * 64 + r;
    size_t o = ((size_t)b * NP + gr) * NP + ln * 4;
    *(float4*)&A[o] = v;
    short tmp[4] = { f2b(v.x), f2b(v.y), f2b(v.z), f2b(v.w) };  // counts <256: exact
    *(short4v*)&Abf[o] = *(short4v*)tmp;
    float s = v.x + v.y + v.z + v.w;
    s += __shfl_xor(s, 1);  s += __shfl_xor(s, 2);  s += __shfl_xor(s, 4);
    s += __shfl_xor(s, 8);  s += __shfl_xor(s, 16); s += __shfl_xor(s, 32);
    if (ln == 0) deg[b * NP + gr] = s;   // integer sum: fp32-exact
  }
}

// ---- hT prep: hThi/hTlo[b][f][n] = bf16 hi/lo split of h[b][n][f] ----
__global__ __launch_bounds__(256) void k_htr(const float* __restrict__ h,
                                             short* __restrict__ hThi,
                                             short* __restrict__ hTlo) {
  __shared__ float T[64][65];
  int b = blockIdx.z, n0 = blockIdx.x * 64, f0 = blockIdx.y * 64;
  int t = threadIdx.x;
  int r = t >> 4, c4 = (t & 15) * 4;
#pragma unroll
  for (int i = 0; i < 4; ++i) {
    float4 v = *(const float4*)&h[((size_t)b * NP + n0 + i * 16 + r) * DI + f0 + c4];
    T[i * 16 + r][c4 + 0] = v.x; T[i * 16 + r][c4 + 1] = v.y;
    T[i * 16 + r][c4 + 2] = v.z; T[i * 16 + r][c4 + 3] = v.w;
  }
  __syncthreads();
#pragma unroll
  for (int i = 0; i < 4; ++i) {
    int f = i * 16 + r;
    short hi4[4], lo4[4];
#pragma unroll
    for (int j = 0; j < 4; ++j) {
      float x = T[c4 + j][f];
      short hb = f2b(x);
      hi4[j] = hb;
      lo4[j] = f2b(x - b2f(hb));
    }
    size_t o = ((size_t)b * DI + f0 + f) * NP + n0 + c4;
    *(short4v*)&hThi[o] = *(short4v*)hi4;
    *(short4v*)&hTlo[o] = *(short4v*)lo4;
  }
}

// ---- agg = rowscale(A @ h) via MFMA bf16, hi/lo split (≈fp32 precision) ----
// block = 32 rows x 256 cols; wave w: rt=w&1 row-tile, fh=w>>1 col-half (8 tiles of 16).
// No LDS, no barriers: afrag/bfrag gathered straight from L2-resident Abf/hT.
__global__ __launch_bounds__(256) void k_gemm_agg(const short* __restrict__ Abf,
                                                  const short* __restrict__ hThi,
                                                  const short* __restrict__ hTlo,
                                                  const float* __restrict__ deg,
                                                  float* __restrict__ agg) {
  int b = blockIdx.y, r0 = blockIdx.x * 32, t = threadIdx.x;
  int wave = t >> 6, lane = t & 63, rt = wave & 1, fh = wave >> 1;
  int m = lane & 15, q = lane >> 4;
  float4v acc[8];
#pragma unroll
  for (int i = 0; i < 8; ++i) acc[i] = (float4v){0.f, 0.f, 0.f, 0.f};
  const short* Ar = &Abf[((size_t)b * NP + r0 + rt * 16 + m) * NP];
  for (int kc = 0; kc < NP; kc += 32) {
    short8 af = *(const short8*)&Ar[kc + q * 8];
#pragma unroll
    for (int tt = 0; tt < 8; ++tt) {
      int f = fh * 128 + tt * 16 + m;
      short8 bh = *(const short8*)&hThi[((size_t)b * DI + f) * NP + kc + q * 8];
      short8 bl = *(const short8*)&hTlo[((size_t)b * DI + f) * NP + kc + q * 8];
      acc[tt] = __builtin_amdgcn_mfma_f32_16x16x32_bf16(af, bh, acc[tt], 0, 0, 0);
      acc[tt] = __builtin_amdgcn_mfma_f32_16x16x32_bf16(af, bl, acc[tt], 0, 0, 0);
    }
  }
#pragma unroll
  for (int reg = 0; reg < 4; ++reg) {
    int row = r0 + rt * 16 + q * 4 + reg;
    float sc = 1.0f / fmaxf(deg[b * NP + row], 1.0f);
#pragma unroll
    for (int tt = 0; tt < 8; ++tt)
      agg[((size_t)b * NP + row) * DI + fh * 128 + tt * 16 + m] = acc[tt][reg] * sc;
  }
}

// ---- Wt[n][k] = bf16(W_head(n)[k][n&127]); Wt is [256][512] shorts, k-contiguous ----
__global__ __launch_bounds__(256) void k_wt(const float* __restrict__ Wf,
                                            const float* __restrict__ Wp,
                                            short* __restrict__ Wt) {
  __shared__ __align__(16) float T[32][132];
  int b = blockIdx.x;          // 0..31
  int head = b >> 4;
  int k0 = (b & 15) * 32;
  const float* W = head ? Wp : Wf;
  int t = threadIdx.x;
  {
    int k = t >> 3, fs = (t & 7) * 16;
    const float* src = &W[(size_t)(k0 + k) * DO + fs];
#pragma unroll
    for (int j = 0; j < 4; ++j)
      *(float4*)&T[k][fs + j * 4] = *(const float4*)(src + j * 4);
  }
  __syncthreads();
  int f = t & 127, kh = (t >> 7) * 16;
  __align__(16) short tmp[16];
#pragma unroll
  for (int i = 0; i < 16; ++i) tmp[i] = f2b(T[kh + i][f]);
  short* dst = &Wt[((size_t)head * DO + f) * 512 + k0 + kh];
  *(short8*)dst = *(short8*)&tmp[0];
  *(short8*)(dst + 8) = *(short8*)&tmp[8];
}

// ---- MFMA zepi: Z = [h|agg]@[Wf|Wp] (bf16 16x16x32), fused bias/norm/relu/softmax ----
// block = 32 rows x 256 cols; wave w: row-tile rt=w&1, head ch=w>>1 (8 col-tiles of 16).
__global__ __launch_bounds__(256) void k_zepi_mfma(const float* __restrict__ h,
                                                   const float* __restrict__ agg,
                                                   const short* __restrict__ Wt,
                                                   const float* __restrict__ bfe,
                                                   const float* __restrict__ bpo,
                                                   float* __restrict__ feat,
                                                   float* __restrict__ assign) {
  __shared__ __align__(16) short Xs[32][40];    // [r][k] bf16, row stride 80 B (16B-aligned)
  int r0 = blockIdx.x * 32;
  int t = threadIdx.x;
  int wave = t >> 6, lane = t & 63;
  int rt = wave & 1, ch = wave >> 1;
  int m = lane & 15, q = lane >> 4;             // frag row/col index, k-quad
  float4v acc[8];
#pragma unroll
  for (int i = 0; i < 8; ++i) acc[i] = (float4v){0.f, 0.f, 0.f, 0.f};

  for (int kc = 0; kc < 2 * DI; kc += 32) {
    __syncthreads();
    {  // stage X chunk (32 rows x 32 k) as bf16
      int r = t >> 3, k4 = (t & 7) * 4;
      const float* src = (kc < DI) ? &h[(size_t)(r0 + r) * DI + kc + k4]
                                   : &agg[(size_t)(r0 + r) * DI + (kc - DI) + k4];
      float4 v = *(const float4*)src;
      Xs[r][k4 + 0] = f2b(v.x); Xs[r][k4 + 1] = f2b(v.y);
      Xs[r][k4 + 2] = f2b(v.z); Xs[r][k4 + 3] = f2b(v.w);
    }
    __syncthreads();
    short8 afrag = *(const short8*)&Xs[rt * 16 + m][q * 8];
#pragma unroll
    for (int tt = 0; tt < 8; ++tt) {
      int n = ch * 128 + tt * 16 + m;
      short8 bfrag = *(const short8*)&Wt[(size_t)n * 512 + kc + q * 8];
      acc[tt] = __builtin_amdgcn_mfma_f32_16x16x32_bf16(afrag, bfrag, acc[tt], 0, 0, 0);
    }
  }

  // epilogue: C/D layout col = tt*16+m, row = q*4+reg (within row-tile)
  const float* bp = ch ? bpo : bfe;
  float bias[8];
#pragma unroll
  for (int tt = 0; tt < 8; ++tt) bias[tt] = bp ? bp[tt * 16 + m] : 0.f;
#pragma unroll
  for (int reg = 0; reg < 4; ++reg) {
    int row = r0 + rt * 16 + q * 4 + reg;
    float z[8];
    float ss = 0.f;
#pragma unroll
    for (int tt = 0; tt < 8; ++tt) { z[tt] = acc[tt][reg] + bias[tt]; ss += z[tt] * z[tt]; }
    ss += __shfl_xor(ss, 1); ss += __shfl_xor(ss, 2);
    ss += __shfl_xor(ss, 4); ss += __shfl_xor(ss, 8);
    float inv = 1.0f / fmaxf(sqrtf(ss), 1e-12f);
    float v[8];
#pragma unroll
    for (int tt = 0; tt < 8; ++tt) v[tt] = fmaxf(z[tt] * inv, 0.f);
    if (ch == 0) {
#pragma unroll
      for (int tt = 0; tt < 8; ++tt) feat[(size_t)row * DO + tt * 16 + m] = v[tt];
    } else {
      float mx = v[0];
#pragma unroll
      for (int tt = 1; tt < 8; ++tt) mx = fmaxf(mx, v[tt]);
      mx = fmaxf(mx, __shfl_xor(mx, 1)); mx = fmaxf(mx, __shfl_xor(mx, 2));
      mx = fmaxf(mx, __shfl_xor(mx, 4)); mx = fmaxf(mx, __shfl_xor(mx, 8));
      float e[8], s = 0.f;
#pragma unroll
      for (int tt = 0; tt < 8; ++tt) { e[tt] = __expf(v[tt] - mx); s += e[tt]; }
      s += __shfl_xor(s, 1); s += __shfl_xor(s, 2);
      s += __shfl_xor(s, 4); s += __shfl_xor(s, 8);
      float is = 1.0f / s;
#pragma unroll
      for (int tt = 0; tt < 8; ++tt) assign[(size_t)row * DO + tt * 16 + m] = e[tt] * is;
    }
  }
}

// ---- AS = A @ assign; tile 64x128, thread 4x8; grid (4, BG)  [508-proven] ----
__global__ __launch_bounds__(256) void k_gemm_as(const float* __restrict__ A,
                                                 const float* __restrict__ assign,
                                                 float* __restrict__ AS) {
  __shared__ __align__(16) float As[32][68];
  __shared__ __align__(16) float Bs[32][132];
  int b = blockIdx.y;
  int r0 = blockIdx.x * 64;
  int t = threadIdx.x;
  int tr = t >> 4, tc = t & 15;
  float acc[4][8] = {};
  const float* Ab = A + (size_t)b * NP * NP;
  const float* asb = assign + (size_t)b * NP * DO;
  for (int kc = 0; kc < NP; kc += 32) {
    __syncthreads();
    {
      int r = t >> 2;
      int ks = (t & 3) * 8;
      const float* src = &Ab[(size_t)(r0 + r) * NP + kc + ks];
      float4 v0 = *(const float4*)src;
      float4 v1 = *(const float4*)(src + 4);
      As[ks + 0][r] = v0.x; As[ks + 1][r] = v0.y; As[ks + 2][r] = v0.z; As[ks + 3][r] = v0.w;
      As[ks + 4][r] = v1.x; As[ks + 5][r] = v1.y; As[ks + 6][r] = v1.z; As[ks + 7][r] = v1.w;
    }
    {
      int k = t >> 3;
      int ls = (t & 7) * 16;
      const float* src = &asb[(size_t)(kc + k) * DO + ls];
#pragma unroll
      for (int j = 0; j < 4; ++j)
        *(float4*)&Bs[k][ls + j * 4] = *(const float4*)(src + j * 4);
    }
    __syncthreads();
#pragma unroll
    for (int k = 0; k < 32; ++k) {
      float a[4], ww[8];
      *(float4*)&a[0] = *(const float4*)&As[k][tr * 4];
      *(float4*)&ww[0] = *(const float4*)&Bs[k][tc * 8];
      *(float4*)&ww[4] = *(const float4*)&Bs[k][tc * 8 + 4];
#pragma unroll
      for (int i = 0; i < 4; ++i)
#pragma unroll
        for (int j = 0; j < 8; ++j)
          acc[i][j] += a[i] * ww[j];
    }
  }
#pragma unroll
  for (int i = 0; i < 4; ++i) {
    float* dst = &AS[((size_t)b * NP + r0 + tr * 4 + i) * DO + tc * 8];
    *(float4*)dst = *(float4*)&acc[i][0];
    *(float4*)(dst + 4) = *(float4*)&acc[i][4];
  }
}

// ---- pooling: out = assign^T @ Y ; 64x128 tile; which 0 -> adj diag, 1 -> hpool [508] --
__global__ __launch_bounds__(256) void k_pool(const float* __restrict__ assign,
                                              const float* __restrict__ AS,
                                              const float* __restrict__ feat,
                                              float* __restrict__ adj,
                                              float* __restrict__ hpool) {
  __shared__ __align__(16) float Ps[32][68];
  __shared__ __align__(16) float Ys[32][132];
  int b = blockIdx.y;
  int mt = blockIdx.x & 1;
  int which = blockIdx.x >> 1;
  const float* Y = which ? feat : AS;
  int m0 = mt * 64;
  int t = threadIdx.x;
  int tr = t >> 4, tc = t & 15;
  float acc[4][8] = {};
  for (int nc = 0; nc < NP; nc += 32) {
    __syncthreads();
    {
      int n = t >> 3;
      int mseg = (t & 7) * 8;
      const float* src = &assign[((size_t)b * NP + nc + n) * DO + m0 + mseg];
      *(float4*)&Ps[n][mseg] = *(const float4*)src;
      *(float4*)&Ps[n][mseg + 4] = *(const float4*)(src + 4);
    }
    {
      int n = t >> 3;
      int ds = (t & 7) * 16;
      const float* src = &Y[((size_t)b * NP + nc + n) * DO + ds];
#pragma unroll
      for (int j = 0; j < 4; ++j)
        *(float4*)&Ys[n][ds + j * 4] = *(const float4*)(src + j * 4);
    }
    __syncthreads();
#pragma unroll
    for (int n = 0; n < 32; ++n) {
      float a[4], ww[8];
      *(float4*)&a[0] = *(const float4*)&Ps[n][tr * 4];
      *(float4*)&ww[0] = *(const float4*)&Ys[n][tc * 8];
      *(float4*)&ww[4] = *(const float4*)&Ys[n][tc * 8 + 4];
#pragma unroll
      for (int i = 0; i < 4; ++i)
#pragma unroll
        for (int j = 0; j < 8; ++j)
          acc[i][j] += a[i] * ww[j];
    }
  }
  if (which == 0) {
#pragma unroll
    for (int i = 0; i < 4; ++i) {
      float* dst = &adj[(size_t)(b * DO + m0 + tr * 4 + i) * (BG * DO) + b * DO + tc * 8];
      *(float4*)dst = *(float4*)&acc[i][0];
      *(float4*)(dst + 4) = *(float4*)&acc[i][4];
    }
  } else {
#pragma unroll
    for (int i = 0; i < 4; ++i) {
      float* dst = &hpool[((size_t)b * DO + m0 + tr * 4 + i) * DO + tc * 8];
      *(float4*)dst = *(float4*)&acc[i][0];
      *(float4*)(dst + 4) = *(float4*)&acc[i][4];
    }
  }
}

extern "C" void kernel_launch(void* const* d_in, const int* in_sizes, int n_in,
                              void* d_out, int out_size, void* d_ws, size_t ws_size,
                              hipStream_t stream) {
  (void)out_size; (void)ws_size;
  int ih = -1, ie[2] = {-1, -1}, iw[2] = {-1, -1}, ib[2] = {-1, -1};
  int ne = 0, nw = 0, nb = 0;
  for (int i = 0; i < n_in; ++i) {
    long long s = in_sizes[i];
    if (s == (long long)BG * NP * DI) { if (ih < 0) ih = i; }
    else if (s == (long long)BG * EP && ne < 2) ie[ne++] = i;
    else if (s == (long long)2 * DI * DO && nw < 2) iw[nw++] = i;
    else if (s == (long long)DO && nb < 2) ib[nb++] = i;
  }
  if (ih < 0 || ne < 2 || nw < 2) {
    ih = 0;
    ie[0] = (n_in > 1) ? 1 : 0;  ie[1] = (n_in > 2) ? 2 : ie[0];
    iw[0] = (n_in > 3) ? 3 : 0;  iw[1] = (n_in > 5) ? 5 : iw[0];
    ib[0] = (n_in > 4) ? 4 : -1; ib[1] = (n_in > 6) ? 6 : -1;
    nb = (ib[1] >= 0) ? 2 : (ib[0] >= 0 ? 1 : 0);
  }
  const float* h    = (const float*)d_in[ih];
  const void* esrc  = d_in[ie[0]];
  const void* edst  = d_in[ie[1]];
  const float* Wf   = (const float*)d_in[iw[0]];
  const float* Wp   = (const float*)d_in[iw[1]];
  const float* bfe  = (nb >= 1) ? (const float*)d_in[ib[0]] : nullptr;
  const float* bpo  = (nb >= 2) ? (const float*)d_in[ib[1]] : nullptr;

  float* adj   = (float*)d_out;
  float* hpool = (float*)d_out + (size_t)(BG * DO) * (BG * DO);
  const size_t ADJ_BYTES = (size_t)(BG * DO) * (BG * DO) * sizeof(float);  // 256 MiB

  // Scratch in d_ws (~84 MiB; harness poison fills indicate ws >= 1 GiB).
  char* wb = (char*)d_ws;
  float* A      = (float*)wb;                            // 16 MiB
  float* agg    = (float*)(wb + 16777216);               // 16 MiB
  float* feat   = (float*)(wb + 33554432);               //  8 MiB
  float* assign = (float*)(wb + 41943040);               //  8 MiB
  float* AS     = (float*)(wb + 50331648);               //  8 MiB
  float* deg    = (float*)(wb + 58720256);               // 64 KiB
  short* Wt     = (short*)(wb + 58720256 + 65536);       // 256 KiB bf16 W^T
  short* Abf    = (short*)(wb + 59047936);               //  8 MiB bf16 A (exact counts)
  short* hThi   = (short*)(wb + 67436544);               //  8 MiB bf16 h^T hi
  short* hTlo   = (short*)(wb + 75825152);               //  8 MiB bf16 h^T lo

  hipMemsetAsync(adj, 0, ADJ_BYTES, stream);
  k_wt<<<32, 256, 0, stream>>>(Wf, Wp, Wt);
  k_htr<<<dim3(4, 4, BG), 256, 0, stream>>>(h, hThi, hTlo);
  k_scatter<<<dim3(4, BG), 256, 0, stream>>>(esrc, edst, A, Abf, deg);
  k_gemm_agg<<<dim3(8, BG), 256, 0, stream>>>(Abf, hThi, hTlo, deg, agg);
  k_zepi_mfma<<<BG * NP / 32, 256, 0, stream>>>(h, agg, Wt, bfe, bpo, feat, assign);
  k_gemm_as<<<dim3(4, BG), 256, 0, stream>>>(A, assign, AS);
  k_pool<<<dim3(4, BG), 256, 0, stream>>>(assign, AS, feat, adj, hpool);
}

// Round 3
// 448.063 us; speedup vs baseline: 1.0543x; 1.0372x over previous
//
#include <hip/hip_runtime.h>
#include <hip/hip_bf16.h>
#include <stdint.h>

#define BG 64     // graphs
#define NP 256    // nodes per graph
#define DI 256    // in features
#define DO 128    // out features = clusters
#define EP 8192   // edges per graph

// ALL float tensors are FP32 (R8 probe-decoded). Edges int32 (+int64 vote).

typedef __attribute__((ext_vector_type(8))) short short8;   // 8 bf16 (4 VGPRs)
typedef __attribute__((ext_vector_type(4))) short short4v;  // 4 bf16 (8 B)
typedef __attribute__((ext_vector_type(4))) float float4v;  // MFMA accumulator

__device__ __forceinline__ int ldi(const void* p, size_t i, int i64) {
  return i64 ? (int)((const long long*)p)[i] : ((const int*)p)[i];
}

// fp32 -> bf16 bits, round-to-nearest-even
__device__ __forceinline__ short f2b(float x) {
  union { float f; unsigned u; } c; c.f = x;
  unsigned r = c.u + 0x7FFFu + ((c.u >> 16) & 1u);
  return (short)(r >> 16);
}
__device__ __forceinline__ float b2f(short b) {
  union { unsigned u; float f; } c; c.u = ((unsigned)(unsigned short)b) << 16;
  return c.f;
}

// uniform int64-vs-int32 vote: upper words of first 8 int64 values are all 0 for int64
// data; for int32 data they are random edge values -> P(all zero) = 2^-64.
__device__ __forceinline__ int vote_i64(const void* esrc) {
  const uint32_t* ew = (const uint32_t*)esrc;
  int i64 = 1;
#pragma unroll
  for (int j = 0; j < 8; ++j)
    if (ew[2 * j + 1] != 0) i64 = 0;
  return i64;
}

// ---- scatter: LDS row slab, no global atomics; writes exact-bf16 Abf + fp32 deg ----
__global__ __launch_bounds__(256) void k_scatter(const void* __restrict__ esrc,
                                                 const void* __restrict__ edst,
                                                 short* __restrict__ Abf,
                                                 float* __restrict__ deg) {
  __shared__ float Asl[64][256];   // exactly 64 KiB
  int b = blockIdx.y, rq = blockIdx.x, t = threadIdx.x;
  float4* Az = (float4*)&Asl[0][0];
  for (int i = t; i < 64 * 256 / 4; i += 256) Az[i] = make_float4(0.f, 0.f, 0.f, 0.f);
  int i64 = vote_i64(esrc);
  __syncthreads();
  const size_t base = (size_t)b * EP;
  for (int e = t; e < EP; e += 256) {
    int si = ldi(esrc, base + e, i64) & (NP - 1);
    int di = ldi(edst, base + e, i64) & (NP - 1);
    if ((di >> 6) == rq) atomicAdd(&Asl[di & 63][si], 1.0f);
  }
  __syncthreads();
  int wv = t >> 6, ln = t & 63;
#pragma unroll
  for (int k = 0; k < 16; ++k) {
    int r = k * 4 + wv;
    float4 v = *(float4*)&Asl[r][ln * 4];
    int gr = rq * 64 + r;
    size_t o = ((size_t)b * NP + gr) * NP + ln * 4;
    short tmp[4] = { f2b(v.x), f2b(v.y), f2b(v.z), f2b(v.w) };  // counts <256: exact
    *(short4v*)&Abf[o] = *(short4v*)tmp;
    float s = v.x + v.y + v.z + v.w;
    s += __shfl_xor(s, 1);  s += __shfl_xor(s, 2);  s += __shfl_xor(s, 4);
    s += __shfl_xor(s, 8);  s += __shfl_xor(s, 16); s += __shfl_xor(s, 32);
    if (ln == 0) deg[b * NP + gr] = s;   // integer sum: fp32-exact
  }
}

// ---- hT prep: hThi/hTlo[b][f][n] = bf16 hi/lo split of h[b][n][f] ----
__global__ __launch_bounds__(256) void k_htr(const float* __restrict__ h,
                                             short* __restrict__ hThi,
                                             short* __restrict__ hTlo) {
  __shared__ float T[64][65];
  int b = blockIdx.z, n0 = blockIdx.x * 64, f0 = blockIdx.y * 64;
  int t = threadIdx.x;
  int r = t >> 4, c4 = (t & 15) * 4;
#pragma unroll
  for (int i = 0; i < 4; ++i) {
    float4 v = *(const float4*)&h[((size_t)b * NP + n0 + i * 16 + r) * DI + f0 + c4];
    T[i * 16 + r][c4 + 0] = v.x; T[i * 16 + r][c4 + 1] = v.y;
    T[i * 16 + r][c4 + 2] = v.z; T[i * 16 + r][c4 + 3] = v.w;
  }
  __syncthreads();
#pragma unroll
  for (int i = 0; i < 4; ++i) {
    int f = i * 16 + r;
    short hi4[4], lo4[4];
#pragma unroll
    for (int j = 0; j < 4; ++j) {
      float x = T[c4 + j][f];
      short hb = f2b(x);
      hi4[j] = hb;
      lo4[j] = f2b(x - b2f(hb));
    }
    size_t o = ((size_t)b * DI + f0 + f) * NP + n0 + c4;
    *(short4v*)&hThi[o] = *(short4v*)hi4;
    *(short4v*)&hTlo[o] = *(short4v*)lo4;
  }
}

// ---- agg = rowscale(A @ h) via MFMA bf16, hi/lo split (fp32-class precision) ----
__global__ __launch_bounds__(256) void k_gemm_agg(const short* __restrict__ Abf,
                                                  const short* __restrict__ hThi,
                                                  const short* __restrict__ hTlo,
                                                  const float* __restrict__ deg,
                                                  float* __restrict__ agg) {
  int b = blockIdx.y, r0 = blockIdx.x * 32, t = threadIdx.x;
  int wave = t >> 6, lane = t & 63, rt = wave & 1, fh = wave >> 1;
  int m = lane & 15, q = lane >> 4;
  float4v acc[8];
#pragma unroll
  for (int i = 0; i < 8; ++i) acc[i] = (float4v){0.f, 0.f, 0.f, 0.f};
  const short* Ar = &Abf[((size_t)b * NP + r0 + rt * 16 + m) * NP];
  for (int kc = 0; kc < NP; kc += 32) {
    short8 af = *(const short8*)&Ar[kc + q * 8];
#pragma unroll
    for (int tt = 0; tt < 8; ++tt) {
      int f = fh * 128 + tt * 16 + m;
      short8 bh = *(const short8*)&hThi[((size_t)b * DI + f) * NP + kc + q * 8];
      short8 bl = *(const short8*)&hTlo[((size_t)b * DI + f) * NP + kc + q * 8];
      acc[tt] = __builtin_amdgcn_mfma_f32_16x16x32_bf16(af, bh, acc[tt], 0, 0, 0);
      acc[tt] = __builtin_amdgcn_mfma_f32_16x16x32_bf16(af, bl, acc[tt], 0, 0, 0);
    }
  }
#pragma unroll
  for (int reg = 0; reg < 4; ++reg) {
    int row = r0 + rt * 16 + q * 4 + reg;
    float sc = 1.0f / fmaxf(deg[b * NP + row], 1.0f);
#pragma unroll
    for (int tt = 0; tt < 8; ++tt)
      agg[((size_t)b * NP + row) * DI + fh * 128 + tt * 16 + m] = acc[tt][reg] * sc;
  }
}

// ---- Wt[n][k] = bf16(W_head(n)[k][n&127]); Wt is [256][512] shorts, k-contiguous ----
__global__ __launch_bounds__(256) void k_wt(const float* __restrict__ Wf,
                                            const float* __restrict__ Wp,
                                            short* __restrict__ Wt) {
  __shared__ __align__(16) float T[32][132];
  int b = blockIdx.x;          // 0..31
  int head = b >> 4;
  int k0 = (b & 15) * 32;
  const float* W = head ? Wp : Wf;
  int t = threadIdx.x;
  {
    int k = t >> 3, fs = (t & 7) * 16;
    const float* src = &W[(size_t)(k0 + k) * DO + fs];
#pragma unroll
    for (int j = 0; j < 4; ++j)
      *(float4*)&T[k][fs + j * 4] = *(const float4*)(src + j * 4);
  }
  __syncthreads();
  int f = t & 127, kh = (t >> 7) * 16;
  __align__(16) short tmp[16];
#pragma unroll
  for (int i = 0; i < 16; ++i) tmp[i] = f2b(T[kh + i][f]);
  short* dst = &Wt[((size_t)head * DO + f) * 512 + k0 + kh];
  *(short8*)dst = *(short8*)&tmp[0];
  *(short8*)(dst + 8) = *(short8*)&tmp[8];
}

// ---- MFMA zepi: Z = [h|agg]@[Wf|Wp], fused bias/norm/relu/softmax; emits TRANSPOSED
// bf16 hi/lo featT (FtH/L) and assignT (PtH/L), node-contiguous [b][col][n]. ----
__global__ __launch_bounds__(256) void k_zepi_mfma(const float* __restrict__ h,
                                                   const float* __restrict__ agg,
                                                   const short* __restrict__ Wt,
                                                   const float* __restrict__ bfe,
                                                   const float* __restrict__ bpo,
                                                   short* __restrict__ FtH,
                                                   short* __restrict__ FtL,
                                                   short* __restrict__ PtH,
                                                   short* __restrict__ PtL) {
  __shared__ __align__(16) short Xs[32][40];          // staging, 2.5 KiB
  __shared__ __align__(16) short TT[2][2][128][40];   // [head][hilo][col][row], 40 KiB
  int r0 = blockIdx.x * 32;
  int t = threadIdx.x;
  int wave = t >> 6, lane = t & 63;
  int rt = wave & 1, ch = wave >> 1;
  int m = lane & 15, q = lane >> 4;
  float4v acc[8];
#pragma unroll
  for (int i = 0; i < 8; ++i) acc[i] = (float4v){0.f, 0.f, 0.f, 0.f};

  for (int kc = 0; kc < 2 * DI; kc += 32) {
    __syncthreads();
    {  // stage X chunk (32 rows x 32 k) as bf16
      int r = t >> 3, k4 = (t & 7) * 4;
      const float* src = (kc < DI) ? &h[(size_t)(r0 + r) * DI + kc + k4]
                                   : &agg[(size_t)(r0 + r) * DI + (kc - DI) + k4];
      float4 v = *(const float4*)src;
      Xs[r][k4 + 0] = f2b(v.x); Xs[r][k4 + 1] = f2b(v.y);
      Xs[r][k4 + 2] = f2b(v.z); Xs[r][k4 + 3] = f2b(v.w);
    }
    __syncthreads();
    short8 afrag = *(const short8*)&Xs[rt * 16 + m][q * 8];
#pragma unroll
    for (int tt = 0; tt < 8; ++tt) {
      int n = ch * 128 + tt * 16 + m;
      short8 bfrag = *(const short8*)&Wt[(size_t)n * 512 + kc + q * 8];
      acc[tt] = __builtin_amdgcn_mfma_f32_16x16x32_bf16(afrag, bfrag, acc[tt], 0, 0, 0);
    }
  }

  // epilogue: C/D layout col = tt*16+m, row = q*4+reg (within row-tile rt)
  const float* bp = ch ? bpo : bfe;
  float bias[8];
#pragma unroll
  for (int tt = 0; tt < 8; ++tt) bias[tt] = bp ? bp[tt * 16 + m] : 0.f;
#pragma unroll
  for (int reg = 0; reg < 4; ++reg) {
    int rloc = rt * 16 + q * 4 + reg;    // 0..31 within block
    float z[8];
    float ss = 0.f;
#pragma unroll
    for (int tt = 0; tt < 8; ++tt) { z[tt] = acc[tt][reg] + bias[tt]; ss += z[tt] * z[tt]; }
    ss += __shfl_xor(ss, 1); ss += __shfl_xor(ss, 2);
    ss += __shfl_xor(ss, 4); ss += __shfl_xor(ss, 8);
    float inv = 1.0f / fmaxf(sqrtf(ss), 1e-12f);
    float v[8];
#pragma unroll
    for (int tt = 0; tt < 8; ++tt) v[tt] = fmaxf(z[tt] * inv, 0.f);
    if (ch == 1) {   // softmax head -> assign values
      float mx = v[0];
#pragma unroll
      for (int tt = 1; tt < 8; ++tt) mx = fmaxf(mx, v[tt]);
      mx = fmaxf(mx, __shfl_xor(mx, 1)); mx = fmaxf(mx, __shfl_xor(mx, 2));
      mx = fmaxf(mx, __shfl_xor(mx, 4)); mx = fmaxf(mx, __shfl_xor(mx, 8));
      float e[8], s = 0.f;
#pragma unroll
      for (int tt = 0; tt < 8; ++tt) { e[tt] = __expf(v[tt] - mx); s += e[tt]; }
      s += __shfl_xor(s, 1); s += __shfl_xor(s, 2);
      s += __shfl_xor(s, 4); s += __shfl_xor(s, 8);
      float is = 1.0f / s;
#pragma unroll
      for (int tt = 0; tt < 8; ++tt) v[tt] = e[tt] * is;
    }
#pragma unroll
    for (int tt = 0; tt < 8; ++tt) {
      short hb = f2b(v[tt]);
      short lb = f2b(v[tt] - b2f(hb));
      TT[ch][0][tt * 16 + m][rloc] = hb;
      TT[ch][1][tt * 16 + m][rloc] = lb;
    }
  }
  __syncthreads();
  // writeout: 2 head x 2 hilo x 128 col x 4 chunks(16B) = 2048 chunks, 8 per thread
  int b = r0 >> 8, nl = r0 & 255;
#pragma unroll
  for (int it = 0; it < 8; ++it) {
    int chunk = it * 256 + t;
    int c = chunk & 3, col = (chunk >> 2) & 127;
    int hl = (chunk >> 9) & 1, head = chunk >> 10;
    short* base = head ? (hl ? PtL : PtH) : (hl ? FtL : FtH);
    short* dst = &base[((size_t)b * DO + col) * NP + nl + c * 8];
    *(short8*)dst = *(const short8*)&TT[head][hl][col][c * 8];
  }
}

// ---- AS = A @ assign via MFMA (A exact bf16, P hi/lo); emits transposed ASt hi/lo ----
__global__ __launch_bounds__(256) void k_gemm_as(const short* __restrict__ Abf,
                                                 const short* __restrict__ PtH,
                                                 const short* __restrict__ PtL,
                                                 short* __restrict__ AStH,
                                                 short* __restrict__ AStL) {
  __shared__ __align__(16) short TS[2][128][40];   // 20 KiB
  int b = blockIdx.y, n0 = blockIdx.x * 32, t = threadIdx.x;
  int wave = t >> 6, lane = t & 63, rt = wave & 1, fh = wave >> 1;
  int m = lane & 15, q = lane >> 4;
  float4v acc[4];
#pragma unroll
  for (int i = 0; i < 4; ++i) acc[i] = (float4v){0.f, 0.f, 0.f, 0.f};
  const short* Ar = &Abf[((size_t)b * NP + n0 + rt * 16 + m) * NP];
  for (int kc = 0; kc < NP; kc += 32) {
    short8 af = *(const short8*)&Ar[kc + q * 8];
#pragma unroll
    for (int tt = 0; tt < 4; ++tt) {
      int j = fh * 64 + tt * 16 + m;
      short8 bh = *(const short8*)&PtH[((size_t)b * DO + j) * NP + kc + q * 8];
      short8 bl = *(const short8*)&PtL[((size_t)b * DO + j) * NP + kc + q * 8];
      acc[tt] = __builtin_amdgcn_mfma_f32_16x16x32_bf16(af, bh, acc[tt], 0, 0, 0);
      acc[tt] = __builtin_amdgcn_mfma_f32_16x16x32_bf16(af, bl, acc[tt], 0, 0, 0);
    }
  }
#pragma unroll
  for (int tt = 0; tt < 4; ++tt) {
#pragma unroll
    for (int reg = 0; reg < 4; ++reg) {
      int j = fh * 64 + tt * 16 + m;
      int nl = rt * 16 + q * 4 + reg;
      float vv = acc[tt][reg];
      short hb = f2b(vv);
      TS[0][j][nl] = hb;
      TS[1][j][nl] = f2b(vv - b2f(hb));
    }
  }
  __syncthreads();
  // writeout: 2 hilo x 128 col x 4 chunks = 1024 chunks, 4 per thread
#pragma unroll
  for (int it = 0; it < 4; ++it) {
    int chunk = it * 256 + t;
    int c = chunk & 3, col = (chunk >> 2) & 127, hl = chunk >> 9;
    short* dst = &(hl ? AStL : AStH)[((size_t)b * DO + col) * NP + n0 + c * 8];
    *(short8*)dst = *(const short8*)&TS[hl][col][c * 8];
  }
}

// ---- pool via MFMA: out = P^T @ Y, 3-term hi/lo (hh+lh+hl). which 0->adj, 1->hpool.
// grid (8, BG): x bits = {ch2 colhalf, rh rowhalf, which}. Block out tile 64x64.
__global__ __launch_bounds__(256) void k_pool2(const short* __restrict__ PtH,
                                               const short* __restrict__ PtL,
                                               const short* __restrict__ AStH,
                                               const short* __restrict__ AStL,
                                               const short* __restrict__ FtH,
                                               const short* __restrict__ FtL,
                                               float* __restrict__ adj,
                                               float* __restrict__ hpool) {
  int b = blockIdx.y;
  int ch2 = blockIdx.x & 1, rh = (blockIdx.x >> 1) & 1, which = blockIdx.x >> 2;
  const short* YH = which ? FtH : AStH;
  const short* YL = which ? FtL : AStL;
  int t = threadIdx.x, wave = t >> 6, lane = t & 63;
  int m = lane & 15, q = lane >> 4;
  float4v acc[4];
#pragma unroll
  for (int i = 0; i < 4; ++i) acc[i] = (float4v){0.f, 0.f, 0.f, 0.f};
  int irow = rh * 64 + wave * 16 + m;    // A-operand row (cluster i)
  const short* pah = &PtH[((size_t)b * DO + irow) * NP];
  const short* pal = &PtL[((size_t)b * DO + irow) * NP];
  for (int kc = 0; kc < NP; kc += 32) {
    short8 ah = *(const short8*)&pah[kc + q * 8];
    short8 al = *(const short8*)&pal[kc + q * 8];
#pragma unroll
    for (int tt = 0; tt < 4; ++tt) {
      int j = ch2 * 64 + tt * 16 + m;
      short8 bh = *(const short8*)&YH[((size_t)b * DO + j) * NP + kc + q * 8];
      short8 bl = *(const short8*)&YL[((size_t)b * DO + j) * NP + kc + q * 8];
      acc[tt] = __builtin_amdgcn_mfma_f32_16x16x32_bf16(ah, bh, acc[tt], 0, 0, 0);
      acc[tt] = __builtin_amdgcn_mfma_f32_16x16x32_bf16(al, bh, acc[tt], 0, 0, 0);
      acc[tt] = __builtin_amdgcn_mfma_f32_16x16x32_bf16(ah, bl, acc[tt], 0, 0, 0);
    }
  }
#pragma unroll
  for (int tt = 0; tt < 4; ++tt) {
#pragma unroll
    for (int reg = 0; reg < 4; ++reg) {
      int i = rh * 64 + wave * 16 + q * 4 + reg;   // C row (cluster i)
      int j = ch2 * 64 + tt * 16 + m;              // C col
      float vv = acc[tt][reg];
      if (which == 0)
        adj[(size_t)(b * DO + i) * (BG * DO) + (size_t)b * DO + j] = vv;
      else
        hpool[((size_t)b * DO + i) * DO + j] = vv;
    }
  }
}

extern "C" void kernel_launch(void* const* d_in, const int* in_sizes, int n_in,
                              void* d_out, int out_size, void* d_ws, size_t ws_size,
                              hipStream_t stream) {
  (void)out_size; (void)ws_size;
  int ih = -1, ie[2] = {-1, -1}, iw[2] = {-1, -1}, ib[2] = {-1, -1};
  int ne = 0, nw = 0, nb = 0;
  for (int i = 0; i < n_in; ++i) {
    long long s = in_sizes[i];
    if (s == (long long)BG * NP * DI) { if (ih < 0) ih = i; }
    else if (s == (long long)BG * EP && ne < 2) ie[ne++] = i;
    else if (s == (long long)2 * DI * DO && nw < 2) iw[nw++] = i;
    else if (s == (long long)DO && nb < 2) ib[nb++] = i;
  }
  if (ih < 0 || ne < 2 || nw < 2) {
    ih = 0;
    ie[0] = (n_in > 1) ? 1 : 0;  ie[1] = (n_in > 2) ? 2 : ie[0];
    iw[0] = (n_in > 3) ? 3 : 0;  iw[1] = (n_in > 5) ? 5 : iw[0];
    ib[0] = (n_in > 4) ? 4 : -1; ib[1] = (n_in > 6) ? 6 : -1;
    nb = (ib[1] >= 0) ? 2 : (ib[0] >= 0 ? 1 : 0);
  }
  const float* h    = (const float*)d_in[ih];
  const void* esrc  = d_in[ie[0]];
  const void* edst  = d_in[ie[1]];
  const float* Wf   = (const float*)d_in[iw[0]];
  const float* Wp   = (const float*)d_in[iw[1]];
  const float* bfe  = (nb >= 1) ? (const float*)d_in[ib[0]] : nullptr;
  const float* bpo  = (nb >= 2) ? (const float*)d_in[ib[1]] : nullptr;

  float* adj   = (float*)d_out;
  float* hpool = (float*)d_out + (size_t)(BG * DO) * (BG * DO);
  const size_t ADJ_BYTES = (size_t)(BG * DO) * (BG * DO) * sizeof(float);  // 256 MiB

  // Scratch in d_ws (~67.5 MiB; ws >= 1 GiB per harness poison fills).
  char* wb = (char*)d_ws;
  float* agg  = (float*)wb;                     // 16 MiB fp32 [b][n][f]
  short* Abf  = (short*)(wb + 16777216);        //  8 MiB bf16 A (exact counts) [b][dst][src]
  short* hThi = (short*)(wb + 25165824);        //  8 MiB bf16 h^T hi [b][f][n]
  short* hTlo = (short*)(wb + 33554432);        //  8 MiB bf16 h^T lo
  short* PtH  = (short*)(wb + 41943040);        //  4 MiB bf16 assign^T hi [b][k][n]
  short* PtL  = (short*)(wb + 46137344);        //  4 MiB
  short* FtH  = (short*)(wb + 50331648);        //  4 MiB bf16 feat^T hi [b][d][n]
  short* FtL  = (short*)(wb + 54525952);        //  4 MiB
  short* AStH = (short*)(wb + 58720256);        //  4 MiB bf16 (A@assign)^T hi [b][k][n]
  short* AStL = (short*)(wb + 62914560);        //  4 MiB
  float* deg  = (float*)(wb + 67108864);        // 64 KiB
  short* Wt   = (short*)(wb + 67174400);        // 256 KiB bf16 W^T

  hipMemsetAsync(adj, 0, ADJ_BYTES, stream);
  k_wt<<<32, 256, 0, stream>>>(Wf, Wp, Wt);
  k_htr<<<dim3(4, 4, BG), 256, 0, stream>>>(h, hThi, hTlo);
  k_scatter<<<dim3(4, BG), 256, 0, stream>>>(esrc, edst, Abf, deg);
  k_gemm_agg<<<dim3(8, BG), 256, 0, stream>>>(Abf, hThi, hTlo, deg, agg);
  k_zepi_mfma<<<BG * NP / 32, 256, 0, stream>>>(h, agg, Wt, bfe, bpo, FtH, FtL, PtH, PtL);
  k_gemm_as<<<dim3(8, BG), 256, 0, stream>>>(Abf, PtH, PtL, AStH, AStL);
  k_pool2<<<dim3(8, BG), 256, 0, stream>>>(PtH, PtL, AStH, AStL, FtH, FtL, adj, hpool);
}

// Round 4
// 415.823 us; speedup vs baseline: 1.1361x; 1.0775x over previous
//
#include <hip/hip_runtime.h>
#include <hip/hip_bf16.h>
#include <stdint.h>

#define BG 64     // graphs
#define NP 256    // nodes per graph
#define DI 256    // in features
#define DO 128    // out features = clusters
#define EP 8192   // edges per graph

// ALL float tensors are FP32 (R8 probe-decoded). Edges int32 (+int64 vote).

typedef __attribute__((ext_vector_type(8))) short short8;   // 8 bf16 (4 VGPRs)
typedef __attribute__((ext_vector_type(4))) short short4v;  // 4 bf16 (8 B)
typedef __attribute__((ext_vector_type(4))) float float4v;  // MFMA accumulator

__device__ __forceinline__ int ldi(const void* p, size_t i, int i64) {
  return i64 ? (int)((const long long*)p)[i] : ((const int*)p)[i];
}

// fp32 -> bf16 bits, round-to-nearest-even
__device__ __forceinline__ short f2b(float x) {
  union { float f; unsigned u; } c; c.f = x;
  unsigned r = c.u + 0x7FFFu + ((c.u >> 16) & 1u);
  return (short)(r >> 16);
}
__device__ __forceinline__ float b2f(short b) {
  union { unsigned u; float f; } c; c.u = ((unsigned)(unsigned short)b) << 16;
  return c.f;
}

// uniform int64-vs-int32 vote: upper words of first 8 int64 values are all 0 for int64
// data; for int32 data they are random edge values -> P(all zero) = 2^-64.
__device__ __forceinline__ int vote_i64(const void* esrc) {
  const uint32_t* ew = (const uint32_t*)esrc;
  int i64 = 1;
#pragma unroll
  for (int j = 0; j < 8; ++j)
    if (ew[2 * j + 1] != 0) i64 = 0;
  return i64;
}

// zero 16 adj rows starting at r0, skipping each row's diagonal 128-col block
// (the diagonal is written by k_pool2 -- disjoint addresses, order-independent).
__device__ __forceinline__ void fill_adj_rows(float* __restrict__ adj, int r0) {
  int t = threadIdx.x;
  const float4v z = {0.f, 0.f, 0.f, 0.f};
  for (int rr = 0; rr < 16; ++rr) {
    int r = r0 + rr;
    int g = r >> 7;                      // graph of this row
    float4v* row = (float4v*)(adj + (size_t)r * (BG * DO));
    int s0 = g * 32;                     // diag float4-range [s0, s0+32)
#pragma unroll
    for (int it = 0; it < 8; ++it) {
      int p = it * 256 + t;
      if ((unsigned)(p - s0) >= 32u)
        __builtin_nontemporal_store(z, &row[p]);
    }
  }
}

// ---- prep: fused htr (1024 blocks) + scatter (256) + wt (32); LDS union 64 KiB ----
__global__ __launch_bounds__(256) void k_prep(const float* __restrict__ h,
                                              const void* __restrict__ esrc,
                                              const void* __restrict__ edst,
                                              const float* __restrict__ Wf,
                                              const float* __restrict__ Wp,
                                              short* __restrict__ hThi,
                                              short* __restrict__ hTlo,
                                              short* __restrict__ Abf,
                                              float* __restrict__ deg,
                                              short* __restrict__ Wt) {
  __shared__ __align__(16) char smem[65536];
  int bx = blockIdx.x, t = threadIdx.x;
  if (bx < 1024) {
    // ---- htr: hThi/hTlo[b][f][n] = bf16 hi/lo split of h[b][n][f] ----
    float (*T)[65] = (float(*)[65])smem;
    int b = bx >> 4, n0 = (bx & 3) * 64, f0 = ((bx >> 2) & 3) * 64;
    int r = t >> 4, c4 = (t & 15) * 4;
#pragma unroll
    for (int i = 0; i < 4; ++i) {
      float4 v = *(const float4*)&h[((size_t)b * NP + n0 + i * 16 + r) * DI + f0 + c4];
      T[i * 16 + r][c4 + 0] = v.x; T[i * 16 + r][c4 + 1] = v.y;
      T[i * 16 + r][c4 + 2] = v.z; T[i * 16 + r][c4 + 3] = v.w;
    }
    __syncthreads();
#pragma unroll
    for (int i = 0; i < 4; ++i) {
      int f = i * 16 + r;
      short hi4[4], lo4[4];
#pragma unroll
      for (int j = 0; j < 4; ++j) {
        float x = T[c4 + j][f];
        short hb = f2b(x);
        hi4[j] = hb;
        lo4[j] = f2b(x - b2f(hb));
      }
      size_t o = ((size_t)b * DI + f0 + f) * NP + n0 + c4;
      *(short4v*)&hThi[o] = *(short4v*)hi4;
      *(short4v*)&hTlo[o] = *(short4v*)lo4;
    }
  } else if (bx < 1280) {
    // ---- scatter: LDS row slab, no global atomics; exact-bf16 Abf + fp32 deg ----
    float (*Asl)[256] = (float(*)[256])smem;   // 64 KiB
    int idx = bx - 1024, b = idx >> 2, rq = idx & 3;
    float4* Az = (float4*)&Asl[0][0];
    for (int i = t; i < 64 * 256 / 4; i += 256) Az[i] = make_float4(0.f, 0.f, 0.f, 0.f);
    int i64 = vote_i64(esrc);
    __syncthreads();
    const size_t base = (size_t)b * EP;
    for (int e = t; e < EP; e += 256) {
      int si = ldi(esrc, base + e, i64) & (NP - 1);
      int di = ldi(edst, base + e, i64) & (NP - 1);
      if ((di >> 6) == rq) atomicAdd(&Asl[di & 63][si], 1.0f);
    }
    __syncthreads();
    int wv = t >> 6, ln = t & 63;
#pragma unroll
    for (int k = 0; k < 16; ++k) {
      int r = k * 4 + wv;
      float4 v = *(float4*)&Asl[r][ln * 4];
      int gr = rq * 64 + r;
      size_t o = ((size_t)b * NP + gr) * NP + ln * 4;
      short tmp[4] = { f2b(v.x), f2b(v.y), f2b(v.z), f2b(v.w) };  // counts <256: exact
      *(short4v*)&Abf[o] = *(short4v*)tmp;
      float s = v.x + v.y + v.z + v.w;
      s += __shfl_xor(s, 1);  s += __shfl_xor(s, 2);  s += __shfl_xor(s, 4);
      s += __shfl_xor(s, 8);  s += __shfl_xor(s, 16); s += __shfl_xor(s, 32);
      if (ln == 0) deg[b * NP + gr] = s;   // integer sum: fp32-exact
    }
  } else {
    // ---- wt: Wt[n][k] = bf16(W_head(n)[k][n&127]); [256][512] shorts, k-contig ----
    float (*T)[132] = (float(*)[132])smem;
    int bb = bx - 1280;          // 0..31
    int head = bb >> 4;
    int k0 = (bb & 15) * 32;
    const float* W = head ? Wp : Wf;
    {
      int k = t >> 3, fs = (t & 7) * 16;
      const float* src = &W[(size_t)(k0 + k) * DO + fs];
#pragma unroll
      for (int j = 0; j < 4; ++j)
        *(float4*)&T[k][fs + j * 4] = *(const float4*)(src + j * 4);
    }
    __syncthreads();
    int f = t & 127, kh = (t >> 7) * 16;
    __align__(16) short tmp[16];
#pragma unroll
    for (int i = 0; i < 16; ++i) tmp[i] = f2b(T[kh + i][f]);
    short* dst = &Wt[((size_t)head * DO + f) * 512 + k0 + kh];
    *(short8*)dst = *(short8*)&tmp[0];
    *(short8*)(dst + 8) = *(short8*)&tmp[8];
  }
}

// ---- fused agg+zepi (+ adj fill rows [0,4096)): per block 32 rows.
// Phase A: agg = rowscale(A@h) via MFMA hi/lo -> bf16 LDS Xa.
// Phase B: Z = [h|Xa]@[Wf|Wp] MFMA, fused bias/norm/relu/softmax; emits transposed
// bf16 hi/lo featT/assignT. LDS: union{ Xa[32][264]+Xs[32][40], TT[2][2][128][40] }.
__global__ __launch_bounds__(256) void k_fz(const float* __restrict__ h,
                                            const short* __restrict__ Abf,
                                            const short* __restrict__ hThi,
                                            const short* __restrict__ hTlo,
                                            const float* __restrict__ deg,
                                            const short* __restrict__ Wt,
                                            const float* __restrict__ bfe,
                                            const float* __restrict__ bpo,
                                            short* __restrict__ FtH, short* __restrict__ FtL,
                                            short* __restrict__ PtH, short* __restrict__ PtL,
                                            float* __restrict__ adj) {
  __shared__ __align__(16) char smem[40960];
  int bx = blockIdx.x, t = threadIdx.x;
  if (bx >= 512) { fill_adj_rows(adj, (bx - 512) * 16); return; }
  short (*Xa)[264] = (short(*)[264])smem;                    // 16896 B (padded rows)
  short (*Xs)[40]  = (short(*)[40])(smem + 16896);           //  2560 B
  short (*TT)[2][128][40] = (short(*)[2][128][40])smem;      // 40960 B (post-barrier)
  int r0 = bx * 32;                  // global row (b*NP + node)
  int b = r0 >> 8, nl = r0 & 255;
  int wave = t >> 6, lane = t & 63;
  int rt = wave & 1, ch = wave >> 1;  // ch: f-half (phase A) / head (phase B)
  int m = lane & 15, q = lane >> 4;
  float4v acc[8];
#pragma unroll
  for (int i = 0; i < 8; ++i) acc[i] = (float4v){0.f, 0.f, 0.f, 0.f};

  // ---- phase A ----
  const short* Ar = &Abf[((size_t)r0 + rt * 16 + m) * NP];
  for (int kc = 0; kc < NP; kc += 32) {
    short8 af = *(const short8*)&Ar[kc + q * 8];
#pragma unroll
    for (int tt = 0; tt < 8; ++tt) {
      int f = ch * 128 + tt * 16 + m;
      short8 bh = *(const short8*)&hThi[((size_t)b * DI + f) * NP + kc + q * 8];
      short8 bl = *(const short8*)&hTlo[((size_t)b * DI + f) * NP + kc + q * 8];
      acc[tt] = __builtin_amdgcn_mfma_f32_16x16x32_bf16(af, bh, acc[tt], 0, 0, 0);
      acc[tt] = __builtin_amdgcn_mfma_f32_16x16x32_bf16(af, bl, acc[tt], 0, 0, 0);
    }
  }
#pragma unroll
  for (int reg = 0; reg < 4; ++reg) {
    int rowl = rt * 16 + q * 4 + reg;
    float sc = 1.0f / fmaxf(deg[r0 + rowl], 1.0f);
#pragma unroll
    for (int tt = 0; tt < 8; ++tt)
      Xa[rowl][ch * 128 + tt * 16 + m] = f2b(acc[tt][reg] * sc);  // same rounding as before
  }
  __syncthreads();

  // ---- phase B ----
#pragma unroll
  for (int i = 0; i < 8; ++i) acc[i] = (float4v){0.f, 0.f, 0.f, 0.f};
  for (int kc = 0; kc < 2 * DI; kc += 32) {
    short8 afrag;
    if (kc < DI) {
      __syncthreads();
      {  // stage h chunk (32 rows x 32 k) as bf16
        int r = t >> 3, k4 = (t & 7) * 4;
        float4 v = *(const float4*)&h[(size_t)(r0 + r) * DI + kc + k4];
        Xs[r][k4 + 0] = f2b(v.x); Xs[r][k4 + 1] = f2b(v.y);
        Xs[r][k4 + 2] = f2b(v.z); Xs[r][k4 + 3] = f2b(v.w);
      }
      __syncthreads();
      afrag = *(const short8*)&Xs[rt * 16 + m][q * 8];
    } else {
      afrag = *(const short8*)&Xa[rt * 16 + m][(kc - DI) + q * 8];
    }
#pragma unroll
    for (int tt = 0; tt < 8; ++tt) {
      int n = ch * 128 + tt * 16 + m;
      short8 bfrag = *(const short8*)&Wt[(size_t)n * 512 + kc + q * 8];
      acc[tt] = __builtin_amdgcn_mfma_f32_16x16x32_bf16(afrag, bfrag, acc[tt], 0, 0, 0);
    }
  }
  __syncthreads();   // all Xa/Xs reads done before TT overwrites the union

  // epilogue: C/D layout col = tt*16+m, row = q*4+reg (within row-tile rt)
  const float* bp = ch ? bpo : bfe;
  float bias[8];
#pragma unroll
  for (int tt = 0; tt < 8; ++tt) bias[tt] = bp ? bp[tt * 16 + m] : 0.f;
#pragma unroll
  for (int reg = 0; reg < 4; ++reg) {
    int rloc = rt * 16 + q * 4 + reg;
    float z[8];
    float ss = 0.f;
#pragma unroll
    for (int tt = 0; tt < 8; ++tt) { z[tt] = acc[tt][reg] + bias[tt]; ss += z[tt] * z[tt]; }
    ss += __shfl_xor(ss, 1); ss += __shfl_xor(ss, 2);
    ss += __shfl_xor(ss, 4); ss += __shfl_xor(ss, 8);
    float inv = 1.0f / fmaxf(sqrtf(ss), 1e-12f);
    float v[8];
#pragma unroll
    for (int tt = 0; tt < 8; ++tt) v[tt] = fmaxf(z[tt] * inv, 0.f);
    if (ch == 1) {   // softmax head -> assign values
      float mx = v[0];
#pragma unroll
      for (int tt = 1; tt < 8; ++tt) mx = fmaxf(mx, v[tt]);
      mx = fmaxf(mx, __shfl_xor(mx, 1)); mx = fmaxf(mx, __shfl_xor(mx, 2));
      mx = fmaxf(mx, __shfl_xor(mx, 4)); mx = fmaxf(mx, __shfl_xor(mx, 8));
      float e[8], s = 0.f;
#pragma unroll
      for (int tt = 0; tt < 8; ++tt) { e[tt] = __expf(v[tt] - mx); s += e[tt]; }
      s += __shfl_xor(s, 1); s += __shfl_xor(s, 2);
      s += __shfl_xor(s, 4); s += __shfl_xor(s, 8);
      float is = 1.0f / s;
#pragma unroll
      for (int tt = 0; tt < 8; ++tt) v[tt] = e[tt] * is;
    }
#pragma unroll
    for (int tt = 0; tt < 8; ++tt) {
      short hb = f2b(v[tt]);
      short lb = f2b(v[tt] - b2f(hb));
      TT[ch][0][tt * 16 + m][rloc] = hb;
      TT[ch][1][tt * 16 + m][rloc] = lb;
    }
  }
  __syncthreads();
  // writeout: 2 head x 2 hilo x 128 col x 4 chunks(16B) = 2048 chunks, 8 per thread
#pragma unroll
  for (int it = 0; it < 8; ++it) {
    int chunk = it * 256 + t;
    int c = chunk & 3, col = (chunk >> 2) & 127;
    int hl = (chunk >> 9) & 1, head = chunk >> 10;
    short* base = head ? (hl ? PtL : PtH) : (hl ? FtL : FtH);
    short* dst = &base[((size_t)b * DO + col) * NP + nl + c * 8];
    *(short8*)dst = *(const short8*)&TT[head][hl][col][c * 8];
  }
}

// ---- AS = A @ assign via MFMA (+ adj fill rows [4096,6144)); transposed ASt hi/lo ----
__global__ __launch_bounds__(256) void k_gemm_as(const short* __restrict__ Abf,
                                                 const short* __restrict__ PtH,
                                                 const short* __restrict__ PtL,
                                                 short* __restrict__ AStH,
                                                 short* __restrict__ AStL,
                                                 float* __restrict__ adj) {
  __shared__ __align__(16) short TS[2][128][40];   // 20 KiB
  int bx = blockIdx.x, t = threadIdx.x;
  if (bx >= 512) { fill_adj_rows(adj, 4096 + (bx - 512) * 16); return; }
  int b = bx >> 3, n0 = (bx & 7) * 32;
  int wave = t >> 6, lane = t & 63, rt = wave & 1, fh = wave >> 1;
  int m = lane & 15, q = lane >> 4;
  float4v acc[4];
#pragma unroll
  for (int i = 0; i < 4; ++i) acc[i] = (float4v){0.f, 0.f, 0.f, 0.f};
  const short* Ar = &Abf[((size_t)b * NP + n0 + rt * 16 + m) * NP];
  for (int kc = 0; kc < NP; kc += 32) {
    short8 af = *(const short8*)&Ar[kc + q * 8];
#pragma unroll
    for (int tt = 0; tt < 4; ++tt) {
      int j = fh * 64 + tt * 16 + m;
      short8 bh = *(const short8*)&PtH[((size_t)b * DO + j) * NP + kc + q * 8];
      short8 bl = *(const short8*)&PtL[((size_t)b * DO + j) * NP + kc + q * 8];
      acc[tt] = __builtin_amdgcn_mfma_f32_16x16x32_bf16(af, bh, acc[tt], 0, 0, 0);
      acc[tt] = __builtin_amdgcn_mfma_f32_16x16x32_bf16(af, bl, acc[tt], 0, 0, 0);
    }
  }
#pragma unroll
  for (int tt = 0; tt < 4; ++tt) {
#pragma unroll
    for (int reg = 0; reg < 4; ++reg) {
      int j = fh * 64 + tt * 16 + m;
      int nlr = rt * 16 + q * 4 + reg;
      float vv = acc[tt][reg];
      short hb = f2b(vv);
      TS[0][j][nlr] = hb;
      TS[1][j][nlr] = f2b(vv - b2f(hb));
    }
  }
  __syncthreads();
#pragma unroll
  for (int it = 0; it < 4; ++it) {
    int chunk = it * 256 + t;
    int c = chunk & 3, col = (chunk >> 2) & 127, hl = chunk >> 9;
    short* dst = &(hl ? AStL : AStH)[((size_t)b * DO + col) * NP + n0 + c * 8];
    *(short8*)dst = *(const short8*)&TS[hl][col][c * 8];
  }
}

// ---- pool via MFMA (+ adj fill rows [6144,8192)): out = P^T @ Y, hi/lo hh+lh+hl ----
__global__ __launch_bounds__(256) void k_pool2(const short* __restrict__ PtH,
                                               const short* __restrict__ PtL,
                                               const short* __restrict__ AStH,
                                               const short* __restrict__ AStL,
                                               const short* __restrict__ FtH,
                                               const short* __restrict__ FtL,
                                               float* __restrict__ adj,
                                               float* __restrict__ hpool) {
  int bx = blockIdx.x, t = threadIdx.x;
  if (bx >= 512) { fill_adj_rows(adj, 6144 + (bx - 512) * 16); return; }
  int b = bx >> 3, x = bx & 7;
  int ch2 = x & 1, rh = (x >> 1) & 1, which = x >> 2;
  const short* YH = which ? FtH : AStH;
  const short* YL = which ? FtL : AStL;
  int wave = t >> 6, lane = t & 63;
  int m = lane & 15, q = lane >> 4;
  float4v acc[4];
#pragma unroll
  for (int i = 0; i < 4; ++i) acc[i] = (float4v){0.f, 0.f, 0.f, 0.f};
  int irow = rh * 64 + wave * 16 + m;
  const short* pah = &PtH[((size_t)b * DO + irow) * NP];
  const short* pal = &PtL[((size_t)b * DO + irow) * NP];
  for (int kc = 0; kc < NP; kc += 32) {
    short8 ah = *(const short8*)&pah[kc + q * 8];
    short8 al = *(const short8*)&pal[kc + q * 8];
#pragma unroll
    for (int tt = 0; tt < 4; ++tt) {
      int j = ch2 * 64 + tt * 16 + m;
      short8 bh = *(const short8*)&YH[((size_t)b * DO + j) * NP + kc + q * 8];
      short8 bl = *(const short8*)&YL[((size_t)b * DO + j) * NP + kc + q * 8];
      acc[tt] = __builtin_amdgcn_mfma_f32_16x16x32_bf16(ah, bh, acc[tt], 0, 0, 0);
      acc[tt] = __builtin_amdgcn_mfma_f32_16x16x32_bf16(al, bh, acc[tt], 0, 0, 0);
      acc[tt] = __builtin_amdgcn_mfma_f32_16x16x32_bf16(ah, bl, acc[tt], 0, 0, 0);
    }
  }
#pragma unroll
  for (int tt = 0; tt < 4; ++tt) {
#pragma unroll
    for (int reg = 0; reg < 4; ++reg) {
      int i = rh * 64 + wave * 16 + q * 4 + reg;
      int j = ch2 * 64 + tt * 16 + m;
      float vv = acc[tt][reg];
      if (which == 0)
        adj[(size_t)(b * DO + i) * (BG * DO) + (size_t)b * DO + j] = vv;
      else
        hpool[((size_t)b * DO + i) * DO + j] = vv;
    }
  }
}

extern "C" void kernel_launch(void* const* d_in, const int* in_sizes, int n_in,
                              void* d_out, int out_size, void* d_ws, size_t ws_size,
                              hipStream_t stream) {
  (void)out_size; (void)ws_size;
  int ih = -1, ie[2] = {-1, -1}, iw[2] = {-1, -1}, ib[2] = {-1, -1};
  int ne = 0, nw = 0, nb = 0;
  for (int i = 0; i < n_in; ++i) {
    long long s = in_sizes[i];
    if (s == (long long)BG * NP * DI) { if (ih < 0) ih = i; }
    else if (s == (long long)BG * EP && ne < 2) ie[ne++] = i;
    else if (s == (long long)2 * DI * DO && nw < 2) iw[nw++] = i;
    else if (s == (long long)DO && nb < 2) ib[nb++] = i;
  }
  if (ih < 0 || ne < 2 || nw < 2) {
    ih = 0;
    ie[0] = (n_in > 1) ? 1 : 0;  ie[1] = (n_in > 2) ? 2 : ie[0];
    iw[0] = (n_in > 3) ? 3 : 0;  iw[1] = (n_in > 5) ? 5 : iw[0];
    ib[0] = (n_in > 4) ? 4 : -1; ib[1] = (n_in > 6) ? 6 : -1;
    nb = (ib[1] >= 0) ? 2 : (ib[0] >= 0 ? 1 : 0);
  }
  const float* h    = (const float*)d_in[ih];
  const void* esrc  = d_in[ie[0]];
  const void* edst  = d_in[ie[1]];
  const float* Wf   = (const float*)d_in[iw[0]];
  const float* Wp   = (const float*)d_in[iw[1]];
  const float* bfe  = (nb >= 1) ? (const float*)d_in[ib[0]] : nullptr;
  const float* bpo  = (nb >= 2) ? (const float*)d_in[ib[1]] : nullptr;

  float* adj   = (float*)d_out;
  float* hpool = (float*)d_out + (size_t)(BG * DO) * (BG * DO);

  // Scratch in d_ws (~50.6 MiB; ws >= 1 GiB per harness poison fills).
  char* wb = (char*)d_ws;
  short* Abf  = (short*)wb;                     //  8 MiB bf16 A (exact counts) [b][dst][src]
  short* hThi = (short*)(wb + 8388608);         //  8 MiB bf16 h^T hi [b][f][n]
  short* hTlo = (short*)(wb + 16777216);        //  8 MiB bf16 h^T lo
  short* PtH  = (short*)(wb + 25165824);        //  4 MiB bf16 assign^T hi [b][k][n]
  short* PtL  = (short*)(wb + 29360128);        //  4 MiB
  short* FtH  = (short*)(wb + 33554432);        //  4 MiB bf16 feat^T hi [b][d][n]
  short* FtL  = (short*)(wb + 37748736);        //  4 MiB
  short* AStH = (short*)(wb + 41943040);        //  4 MiB bf16 (A@assign)^T hi [b][k][n]
  short* AStL = (short*)(wb + 46137344);        //  4 MiB
  float* deg  = (float*)(wb + 50331648);        // 64 KiB
  short* Wt   = (short*)(wb + 50397184);        // 256 KiB bf16 W^T

  k_prep<<<1312, 256, 0, stream>>>(h, esrc, edst, Wf, Wp, hThi, hTlo, Abf, deg, Wt);
  k_fz<<<768, 256, 0, stream>>>(h, Abf, hThi, hTlo, deg, Wt, bfe, bpo,
                                FtH, FtL, PtH, PtL, adj);
  k_gemm_as<<<640, 256, 0, stream>>>(Abf, PtH, PtL, AStH, AStL, adj);
  k_pool2<<<640, 256, 0, stream>>>(PtH, PtL, AStH, AStL, FtH, FtL, adj, hpool);
}